// Round 11
// baseline (106.796 us; speedup 1.0000x reference)
//
#include <hip/hip_runtime.h>
#include <hip/hip_bf16.h>
#include <math.h>

typedef __bf16 bf16x8 __attribute__((ext_vector_type(8)));
typedef float  f32x4  __attribute__((ext_vector_type(4)));
typedef unsigned int u32x4 __attribute__((ext_vector_type(4)));

#define MFMA16(a,b,c) __builtin_amdgcn_mfma_f32_16x16x32_bf16(a,b,c,0,0,0)

// inline-asm 16B global load: NOT rematerializable/sinkable by the scheduler.
#define GLOAD(dst, ptr, OFF)                                                  \
    asm volatile("global_load_dwordx4 %0, %1, off offset:" #OFF               \
                 : "=v"(dst) : "v"(ptr) : "memory")

__device__ __forceinline__ float gelu_exact(float x){
    return 0.5f * x * (1.0f + erff(x * 0.7071067811865476f));
}

// ---------- K0: transpose f32 [K][N] -> bf16 [N][K] ----------
__global__ void transp_bf16(const float* __restrict__ src, __bf16* __restrict__ dst,
                            int K, int N){
    int k0 = blockIdx.x * 8;
    int n  = threadIdx.x;
    if (n >= N) return;
    bf16x8 v;
#pragma unroll
    for (int r = 0; r < 8; ++r)
        v[r] = (__bf16)src[(size_t)(k0 + r) * N + n];
    *(bf16x8*)&dst[(size_t)n * K + k0] = v;
}

// ---------- K1: H1 = gelu(LN(X @ W1 + b1)) ----------
// R11: register-resident B via inline-asm loads (no B LDS at all).
// BM=64, BN=256, BK=64, 8 waves (2M x 4N, 32x64 tiles), grid=256.
// Per step: issue asm A(t+1)x2 then asm B(t+1)x8 -> vmcnt(10) [B(t) ready]
// -> COMPUTE (2 ds_read + 16 MFMA per wave) -> vmcnt(8) [A(t+1) ready]
// -> ds_write A -> lgkmcnt(0) + raw s_barrier (B loads stay in flight).
__global__ __launch_bounds__(512, 1) void gemm1_ln_gelu(
    const float* __restrict__ X, const __bf16* __restrict__ W1T,
    const float* __restrict__ b1, const float* __restrict__ g1,
    const float* __restrict__ be1, __bf16* __restrict__ H1)
{
    __shared__ __bf16 lA[2][64*64];     // 16 KB total
    __shared__ float  redS[64][4];
    __shared__ float  redQ[64][4];

    const int tid  = threadIdx.x;
    const int wid  = tid >> 6;
    const int lane = tid & 63;
    const int l15  = lane & 15;
    const int lg   = lane >> 4;
    const int wm   = wid >> 2;       // 0..1
    const int wn   = wid & 3;        // 0..3
    const int mBase = blockIdx.x * 64;

    // A staging: 512 thr cover 64 rows x 64 k, 8 f32 each
    const int sRow = tid >> 3;
    const int sC8  = (tid & 7) * 8;
    const int sDst = sRow * 64 + (sC8 ^ ((sRow & 7) << 3));
    const float* aSrc = X + (size_t)(mBase + sRow) * 2048 + sC8;

    // B fragment pointers (per wave): col = wn*64 + n*16 + l15, k-offset lg*8
    const __bf16* bP0 = W1T + (size_t)(wn*64 +  0 + l15) * 2048 + lg*8;
    const __bf16* bP1 = W1T + (size_t)(wn*64 + 16 + l15) * 2048 + lg*8;
    const __bf16* bP2 = W1T + (size_t)(wn*64 + 32 + l15) * 2048 + lg*8;
    const __bf16* bP3 = W1T + (size_t)(wn*64 + 48 + l15) * 2048 + lg*8;

    f32x4 acc[2][4] = {};
    u32x4 Ba[8], Bb[8];        // two named B banks (compile-time indices only)
    u32x4 A0, A1;              // A in-flight regs (live within one step)

    // issue A(T)x2 FIRST, then B(T)x8 (in-order vmcnt: A drains at vmcnt(8))
#define ISSUE(T, BANK) {                                                     \
        const void* _ap = (const void*)(aSrc + (size_t)(T)*64);              \
        GLOAD(A0, _ap, 0);                                                   \
        GLOAD(A1, _ap, 16);                                                  \
        const void* _b0 = (const void*)(bP0 + (size_t)(T)*64);               \
        const void* _b1 = (const void*)(bP1 + (size_t)(T)*64);               \
        const void* _b2 = (const void*)(bP2 + (size_t)(T)*64);               \
        const void* _b3 = (const void*)(bP3 + (size_t)(T)*64);               \
        GLOAD(BANK[0], _b0, 0);   GLOAD(BANK[1], _b1, 0);                    \
        GLOAD(BANK[2], _b2, 0);   GLOAD(BANK[3], _b3, 0);                    \
        GLOAD(BANK[4], _b0, 64);  GLOAD(BANK[5], _b1, 64);                   \
        GLOAD(BANK[6], _b2, 64);  GLOAD(BANK[7], _b3, 64);                   \
        __builtin_amdgcn_sched_barrier(0); }

#define WRITEA(BUF) {                                                        \
        float4 a0_ = __builtin_bit_cast(float4, A0);                         \
        float4 a1_ = __builtin_bit_cast(float4, A1);                         \
        bf16x8 v;                                                            \
        v[0]=(__bf16)a0_.x; v[1]=(__bf16)a0_.y; v[2]=(__bf16)a0_.z;          \
        v[3]=(__bf16)a0_.w; v[4]=(__bf16)a1_.x; v[5]=(__bf16)a1_.y;          \
        v[6]=(__bf16)a1_.z; v[7]=(__bf16)a1_.w;                              \
        *(bf16x8*)&lA[BUF][sDst] = v; }

#define COMPUTE(CL, BANK) {                                                  \
        _Pragma("unroll")                                                    \
        for (int kk = 0; kk < 2; ++kk){                                      \
            const int kx = (kk*32 + lg*8) ^ ((l15 & 7) << 3);                \
            bf16x8 av0 = *(const bf16x8*)&lA[CL][(wm*32      + l15)*64 + kx];\
            bf16x8 av1 = *(const bf16x8*)&lA[CL][(wm*32 + 16 + l15)*64 + kx];\
            acc[0][0] = MFMA16(av0, __builtin_bit_cast(bf16x8, BANK[kk*4+0]), acc[0][0]); \
            acc[0][1] = MFMA16(av0, __builtin_bit_cast(bf16x8, BANK[kk*4+1]), acc[0][1]); \
            acc[0][2] = MFMA16(av0, __builtin_bit_cast(bf16x8, BANK[kk*4+2]), acc[0][2]); \
            acc[0][3] = MFMA16(av0, __builtin_bit_cast(bf16x8, BANK[kk*4+3]), acc[0][3]); \
            acc[1][0] = MFMA16(av1, __builtin_bit_cast(bf16x8, BANK[kk*4+0]), acc[1][0]); \
            acc[1][1] = MFMA16(av1, __builtin_bit_cast(bf16x8, BANK[kk*4+1]), acc[1][1]); \
            acc[1][2] = MFMA16(av1, __builtin_bit_cast(bf16x8, BANK[kk*4+2]), acc[1][2]); \
            acc[1][3] = MFMA16(av1, __builtin_bit_cast(bf16x8, BANK[kk*4+3]), acc[1][3]); \
        } }

    // STEP t: prefetch t+1 into NXTB; compute t from CURB + lA[CL]; write A(t+1)->lA[NL]
#define STEP(T, CURB, NXTB, CL, NL) {                                        \
        ISSUE((T)+1, NXTB);                                                  \
        asm volatile("s_waitcnt vmcnt(10)" ::: "memory");                    \
        COMPUTE(CL, CURB);                                                   \
        asm volatile("s_waitcnt vmcnt(8)" ::: "memory");                     \
        WRITEA(NL);                                                          \
        asm volatile("s_waitcnt lgkmcnt(0)" ::: "memory");                   \
        __builtin_amdgcn_s_barrier();                                        \
        __builtin_amdgcn_sched_barrier(0); }

    // ---- prologue: A(0),B(0) -> write lA[0]; B(0) stays in flight ----
    ISSUE(0, Ba);
    asm volatile("s_waitcnt vmcnt(8)" ::: "memory");   // A(0) landed
    WRITEA(0);
    asm volatile("s_waitcnt lgkmcnt(0)" ::: "memory");
    __builtin_amdgcn_s_barrier();
    __builtin_amdgcn_sched_barrier(0);

    // ---- steps 0..29 (2-unrolled: banks/bufs alternate) ----
    for (int it = 0; it < 15; ++it){
        const int t = 2*it;
        STEP(t,   Ba, Bb, 0, 1);
        STEP(t+1, Bb, Ba, 1, 0);
    }
    // ---- step 30 (prefetches 31 into Bb) ----
    STEP(30, Ba, Bb, 0, 1);
    // ---- step 31: last compute ----
    asm volatile("s_waitcnt vmcnt(0)" ::: "memory");
    COMPUTE(1, Bb);

    // ---- epilogue: +b1, LayerNorm(256), gelu, store bf16 ----
    float bias_[4], g1_[4], be_[4];
#pragma unroll
    for (int n = 0; n < 4; ++n){
        int col = wn*64 + n*16 + l15;
        bias_[n] = b1[col]; g1_[n] = g1[col]; be_[n] = be1[col];
    }
#pragma unroll
    for (int m = 0; m < 2; ++m)
#pragma unroll
        for (int n = 0; n < 4; ++n)
#pragma unroll
            for (int r = 0; r < 4; ++r)
                acc[m][n][r] += bias_[n];

#pragma unroll
    for (int m = 0; m < 2; ++m)
#pragma unroll
        for (int r = 0; r < 4; ++r){
            float s = 0.f, q = 0.f;
#pragma unroll
            for (int n = 0; n < 4; ++n){ float v = acc[m][n][r]; s += v; q += v*v; }
#pragma unroll
            for (int off = 1; off <= 8; off <<= 1){
                s += __shfl_xor(s, off, 64);
                q += __shfl_xor(q, off, 64);
            }
            int row = wm*32 + m*16 + lg*4 + r;
            if (l15 == 0){ redS[row][wn] = s; redQ[row][wn] = q; }
        }
    __syncthreads();

#pragma unroll
    for (int m = 0; m < 2; ++m)
#pragma unroll
        for (int r = 0; r < 4; ++r){
            int row = wm*32 + m*16 + lg*4 + r;
            float su = redS[row][0]+redS[row][1]+redS[row][2]+redS[row][3];
            float qu = redQ[row][0]+redQ[row][1]+redQ[row][2]+redQ[row][3];
            float mu  = su * (1.f/256.f);
            float var = qu * (1.f/256.f) - mu*mu;
            float rs  = rsqrtf(var + 1e-5f);
            size_t base = (size_t)(mBase + row) * 256;
#pragma unroll
            for (int n = 0; n < 4; ++n){
                float x  = acc[m][n][r];
                float xn = (x - mu) * rs * g1_[n] + be_[n];
                H1[base + wn*64 + n*16 + l15] = (__bf16)gelu_exact(xn);
            }
        }
#undef ISSUE
#undef WRITEA
#undef COMPUTE
#undef STEP
}

// ---------- K2: adjusted = softmax((base + 0.1*tanh(W3^T gelu(LN(H1@W2+b2)) + b3))/temp) ----------
__global__ __launch_bounds__(512) void tail_fused(
    const __bf16* __restrict__ H1, const __bf16* __restrict__ W2T,
    const float* __restrict__ b2, const float* __restrict__ g2,
    const float* __restrict__ be2, const float* __restrict__ W3,
    const float* __restrict__ b3, const int* __restrict__ labels,
    const float* __restrict__ temperature, float* __restrict__ ADJ)
{
    __shared__ union { __bf16 lH[64*256]; float h2[64*128]; } u;
    __shared__ __bf16 lW[128*256];
    __shared__ float  redS[64][4];
    __shared__ float  redQ[64][4];
    __shared__ float  lw3[256];

    const int tid  = threadIdx.x;
    const int wid  = tid >> 6;
    const int lane = tid & 63;
    const int l15  = lane & 15;
    const int lg   = lane >> 4;
    const int wm   = wid >> 2, wn = wid & 3;
    const int mBase = blockIdx.x * 64;

    {
        int r0 = tid >> 5;
        int c8 = (tid & 31) * 8;
        int swz = c8 ^ ((r0 & 7) << 3);
#pragma unroll
        for (int i = 0; i < 4; ++i){
            int row = r0 + i*16;
            bf16x8 v = *(const bf16x8*)&H1[(size_t)(mBase+row)*256 + c8];
            *(bf16x8*)&u.lH[row*256 + swz] = v;
        }
#pragma unroll
        for (int i = 0; i < 8; ++i){
            int row = r0 + i*16;
            bf16x8 v = *(const bf16x8*)&W2T[(size_t)row*256 + c8];
            *(bf16x8*)&lW[row*256 + swz] = v;
        }
        if (tid < 256) lw3[tid] = W3[tid];
    }
    __syncthreads();

    f32x4 acc[2][2] = {};
#pragma unroll
    for (int kk = 0; kk < 8; ++kk){
        const int kcol = kk*32 + lg*8;
        bf16x8 av[2], bv[2];
#pragma unroll
        for (int m = 0; m < 2; ++m){
            int row = wm*32 + m*16 + l15;
            av[m] = *(const bf16x8*)&u.lH[row*256 + (kcol ^ ((row&7)<<3))];
        }
#pragma unroll
        for (int n = 0; n < 2; ++n){
            int row = wn*32 + n*16 + l15;
            bv[n] = *(const bf16x8*)&lW[row*256 + (kcol ^ ((row&7)<<3))];
        }
#pragma unroll
        for (int m = 0; m < 2; ++m)
#pragma unroll
            for (int n = 0; n < 2; ++n)
                acc[m][n] = MFMA16(av[m], bv[n], acc[m][n]);
    }

    float b2_[2], g2_[2], be_[2];
#pragma unroll
    for (int n = 0; n < 2; ++n){
        int col = wn*32 + n*16 + l15;
        b2_[n] = b2[col]; g2_[n] = g2[col]; be_[n] = be2[col];
    }
#pragma unroll
    for (int m = 0; m < 2; ++m)
#pragma unroll
        for (int n = 0; n < 2; ++n)
#pragma unroll
            for (int r = 0; r < 4; ++r)
                acc[m][n][r] += b2_[n];

#pragma unroll
    for (int m = 0; m < 2; ++m)
#pragma unroll
        for (int r = 0; r < 4; ++r){
            float s = 0.f, q = 0.f;
#pragma unroll
            for (int n = 0; n < 2; ++n){ float v = acc[m][n][r]; s += v; q += v*v; }
#pragma unroll
            for (int off = 1; off <= 8; off <<= 1){
                s += __shfl_xor(s, off, 64);
                q += __shfl_xor(q, off, 64);
            }
            int row = wm*32 + m*16 + lg*4 + r;
            if (l15 == 0){ redS[row][wn] = s; redQ[row][wn] = q; }
        }
    __syncthreads();

#pragma unroll
    for (int m = 0; m < 2; ++m)
#pragma unroll
        for (int r = 0; r < 4; ++r){
            int row = wm*32 + m*16 + lg*4 + r;
            float su = redS[row][0]+redS[row][1]+redS[row][2]+redS[row][3];
            float qu = redQ[row][0]+redQ[row][1]+redQ[row][2]+redQ[row][3];
            float mu  = su * (1.f/128.f);
            float var = qu * (1.f/128.f) - mu*mu;
            float rs  = rsqrtf(var + 1e-5f);
#pragma unroll
            for (int n = 0; n < 2; ++n){
                int col = wn*32 + n*16 + l15;
                float x = acc[m][n][r];
                float h = gelu_exact((x - mu)*rs*g2_[n] + be_[n]);
                u.h2[row*128 + (col ^ (row & 31))] = h;
            }
        }
    __syncthreads();

    if (tid < 64){
        const int row = tid;
        const int g = mBase + row;
        float a0 = b3[0], a1 = b3[1];
        for (int k = 0; k < 128; ++k){
            float v = u.h2[row*128 + (k ^ (row & 31))];
            a0 += v * lw3[2*k];
            a1 += v * lw3[2*k+1];
        }
        float t = fmaxf(temperature[0], 0.1f);
        float adj0 = tanhf(a0) * 0.1f;
        float adj1 = tanhf(a1) * 0.1f;
        bool crit = labels[g] > 0;
        float base0 = crit ? 0.25f : 0.75f;
        float base1 = crit ? 0.75f : 0.25f;
        float L0 = (base0 + adj0) / t, L1 = (base1 + adj1) / t;
        float mm = fmaxf(L0, L1);
        float e0 = expf(L0 - mm), e1 = expf(L1 - mm);
        float inv = 1.f / (e0 + e1);
        ADJ[(size_t)g*2    ] = e0 * inv;
        ADJ[(size_t)g*2 + 1] = e1 * inv;
    }
}

// ---------- K3: EMA as 128-tap truncated convolution ----------
__global__ void ema_kernel(const float* __restrict__ ADJ, float* __restrict__ out)
{
    __shared__ float wtab[128];
    __shared__ float abuf[384*2];
    const int b     = blockIdx.x >> 2;
    const int chunk = blockIdx.x & 3;
    const int c0    = chunk * 256;
    const int tid   = threadIdx.x;
    if (tid < 128) wtab[tid] = powf(0.9f, (float)tid);
    for (int idx = tid; idx < 768; idx += 256){
        int tt = c0 - 128 + (idx >> 1);
        int cc = idx & 1;
        abuf[idx] = (tt >= 0) ? ADJ[((size_t)b*1024 + tt)*2 + cc] : 0.f;
    }
    __syncthreads();
#pragma unroll
    for (int i = 0; i < 2; ++i){
        int item = tid + i*256;
        int tl = item >> 1, cc = item & 1;
        int t = c0 + tl;
        int kmax = min(t, 127);
        float sum = 0.f;
        for (int k = 0; k <= kmax; ++k){
            float coef = (t - k == 0) ? wtab[k] : 0.1f * wtab[k];
            sum += coef * abuf[(tl - k + 128)*2 + cc];
        }
        out[((size_t)b*1024 + t)*2 + cc] = sum;
    }
}

extern "C" void kernel_launch(void* const* d_in, const int* in_sizes, int n_in,
                              void* d_out, int out_size, void* d_ws, size_t ws_size,
                              hipStream_t stream)
{
    const int*   labels = (const int*)  d_in[0];
    const float* X      = (const float*)d_in[1];
    const float* W1     = (const float*)d_in[2];
    const float* b1     = (const float*)d_in[3];
    const float* g1     = (const float*)d_in[4];
    const float* be1    = (const float*)d_in[5];
    const float* W2     = (const float*)d_in[6];
    const float* b2     = (const float*)d_in[7];
    const float* g2     = (const float*)d_in[8];
    const float* be2    = (const float*)d_in[9];
    const float* W3     = (const float*)d_in[10];
    const float* b3     = (const float*)d_in[11];
    const float* temp   = (const float*)d_in[12];
    float* out = (float*)d_out;

    char* ws = (char*)d_ws;
    __bf16* W1T = (__bf16*)(ws);                 // 256 x 2048 bf16  (1 MiB)
    __bf16* W2T = (__bf16*)(ws + 1048576);       // 128 x 256  bf16  (64 KiB)
    __bf16* H1  = (__bf16*)(ws + 1114112);       // 16384 x 256 bf16 (8 MiB)
    float*  ADJ = (float*)(ws + 9502720);        // 16384 x 2 f32    (128 KiB)

    transp_bf16<<<256, 256, 0, stream>>>(W1, W1T, 2048, 256);
    transp_bf16<<<32,  256, 0, stream>>>(W2, W2T, 256, 128);
    gemm1_ln_gelu<<<256, 512, 0, stream>>>(X, W1T, b1, g1, be1, H1);
    tail_fused<<<256, 512, 0, stream>>>(H1, W2T, b2, g2, be2, W3, b3, labels, temp, ADJ);
    ema_kernel<<<64, 256, 0, stream>>>(ADJ, out);
}

// Round 12
// 86.828 us; speedup vs baseline: 1.2300x; 1.2300x over previous
//
#include <hip/hip_runtime.h>
#include <hip/hip_bf16.h>
#include <math.h>

typedef __bf16 bf16x8 __attribute__((ext_vector_type(8)));
typedef __bf16 bf16x4 __attribute__((ext_vector_type(4)));
typedef float  f32x4  __attribute__((ext_vector_type(4)));

#define MFMA16(a,b,c) __builtin_amdgcn_mfma_f32_16x16x32_bf16(a,b,c,0,0,0)

__device__ __forceinline__ float gelu_exact(float x){
    return 0.5f * x * (1.0f + erff(x * 0.7071067811865476f));
}

__device__ __forceinline__ void gld_lds16(const void* g, void* l){
    __builtin_amdgcn_global_load_lds(
        (const __attribute__((address_space(1))) unsigned int*)g,
        (__attribute__((address_space(3))) unsigned int*)l, 16, 0, 0);
}

// ---------- K0: transpose f32 [K][N] -> bf16 [N][K] ----------
__global__ void transp_bf16(const float* __restrict__ src, __bf16* __restrict__ dst,
                            int K, int N){
    int k0 = blockIdx.x * 8;
    int n  = threadIdx.x;
    if (n >= N) return;
    bf16x8 v;
#pragma unroll
    for (int r = 0; r < 8; ++r)
        v[r] = (__bf16)src[(size_t)(k0 + r) * N + n];
    *(bf16x8*)&dst[(size_t)n * K + k0] = v;
}

// ---------- K1: partial = X[:, khalf] @ W1[khalf, :]  (pre-LN, bf16) ----------
// R12: traffic fix. Wave tile 64x64 (LDS reads 96->64 KB/unit), BM=128/BN=256/
// 8 waves, split-K=2 (grid=256, 16 steps, no X re-read). R5 counted-vmcnt
// skeleton: per step 4 A-loads + 4 B-DMAs -> vmcnt(8), never 0 in main loop.
// LN moved to a second pass (rows need both K-halves).
__global__ __launch_bounds__(512, 1) void gemm1_pre(
    const float* __restrict__ X, const __bf16* __restrict__ W1T,
    __bf16* __restrict__ H1p)
{
    __shared__ __bf16 lA[2][128*64];    // 32 KB
    __shared__ __bf16 lB[3][256*64];    // 96 KB

    const int tid  = threadIdx.x;
    const int wid  = tid >> 6;
    const int lane = tid & 63;
    const int l15  = lane & 15;
    const int lg   = lane >> 4;
    const int wm   = wid >> 2;        // 0..1 (M half)
    const int wn   = wid & 3;         // 0..3 (N quarter)
    const int mBase = (blockIdx.x >> 1) * 128;
    const int kBlk  = blockIdx.x & 1;
    const int kBase = kBlk << 10;     // 0 or 1024

    // ---- A staging: 128 rows x 64 k f32 per step; 4 dwordx4 per thread ----
    const int sRow = tid >> 2;                  // 0..127
    const int sQ   = (tid & 3) * 16;            // 0,16,32,48
    const int swzA = (sRow & 7) << 3;
    const float* aSrc = X + (size_t)(mBase + sRow) * 2048 + kBase + sQ;

    // ---- B staging: 256 rows x 64 k bf16 = 32KB/step; 4 gld_lds per thread ----
    // LDS slot s of row holds global k-chunk s^(row&7) (read-path XOR)
    const __bf16* bSrc[4];
    int ldsOff[4];
#pragma unroll
    for (int r = 0; r < 4; ++r){
        int j   = tid + r*512;                  // 0..2047
        int row = j >> 3;                       // 0..255
        int c   = (j & 7) ^ (row & 7);
        bSrc[r] = W1T + (size_t)row * 2048 + kBase + c*8;
        ldsOff[r] = __builtin_amdgcn_readfirstlane(wid*1024 + r*8192);  // bytes
    }

    f32x4 acc[4][4] = {};
    float4 pA[4], nA[4];

#define ISSUEA(BANK, T) {                                                    \
        _Pragma("unroll")                                                    \
        for (int i = 0; i < 4; ++i)                                          \
            BANK[i] = *(const float4*)(aSrc + (size_t)(T)*64 + i*4); }

#define STAGEB(BUF, KT) {                                                    \
        char* _lb = (char*)&lB[BUF][0];                                      \
        _Pragma("unroll")                                                    \
        for (int r = 0; r < 4; ++r)                                          \
            gld_lds16(bSrc[r] + (size_t)(KT)*64, _lb + ldsOff[r]); }

#define WRITEA(BUF, BANK) {                                                  \
        bf16x8 v0, v1;                                                       \
        v0[0]=(__bf16)BANK[0].x; v0[1]=(__bf16)BANK[0].y;                    \
        v0[2]=(__bf16)BANK[0].z; v0[3]=(__bf16)BANK[0].w;                    \
        v0[4]=(__bf16)BANK[1].x; v0[5]=(__bf16)BANK[1].y;                    \
        v0[6]=(__bf16)BANK[1].z; v0[7]=(__bf16)BANK[1].w;                    \
        v1[0]=(__bf16)BANK[2].x; v1[1]=(__bf16)BANK[2].y;                    \
        v1[2]=(__bf16)BANK[2].z; v1[3]=(__bf16)BANK[2].w;                    \
        v1[4]=(__bf16)BANK[3].x; v1[5]=(__bf16)BANK[3].y;                    \
        v1[6]=(__bf16)BANK[3].z; v1[7]=(__bf16)BANK[3].w;                    \
        *(bf16x8*)&lA[BUF][sRow*64 + ( sQ      ^ swzA)] = v0;                \
        *(bf16x8*)&lA[BUF][sRow*64 + ((sQ + 8) ^ swzA)] = v1; }

#define COMPUTE(CA, CB) {                                                    \
        _Pragma("unroll")                                                    \
        for (int kk = 0; kk < 2; ++kk){                                      \
            const int kx = (kk*32 + lg*8) ^ ((l15 & 7) << 3);                \
            bf16x8 av[4], bv[4];                                             \
            _Pragma("unroll")                                                \
            for (int m = 0; m < 4; ++m)                                      \
                av[m] = *(const bf16x8*)&lA[CA][(wm*64 + m*16 + l15)*64 + kx]; \
            _Pragma("unroll")                                                \
            for (int n = 0; n < 4; ++n)                                      \
                bv[n] = *(const bf16x8*)&lB[CB][(wn*64 + n*16 + l15)*64 + kx]; \
            _Pragma("unroll")                                                \
            for (int m = 0; m < 4; ++m)                                      \
                _Pragma("unroll")                                            \
                for (int n = 0; n < 4; ++n)                                  \
                    acc[m][n] = MFMA16(av[m], bv[n], acc[m][n]);             \
        } }

    // STEP t: issue A(t+2)->NB, DMA B(t+2); COMPUTE(t); ds_write A(t+1) from PB;
    // vmcnt(8) keeps {A(t+2),B(t+2)} in flight across the barrier.
#define STEP(PB, NB)                                                         \
    {                                                                        \
        int bn = bc + 2; if (bn >= 3) bn -= 3;                               \
        ISSUEA(NB, t+2);                                                     \
        __builtin_amdgcn_sched_barrier(0);                                   \
        STAGEB(bn, t+2);                                                     \
        __builtin_amdgcn_sched_barrier(0);                                   \
        COMPUTE(t & 1, bc);                                                  \
        __builtin_amdgcn_sched_barrier(0);                                   \
        WRITEA((t+1) & 1, PB);                                               \
        asm volatile("s_waitcnt vmcnt(8) lgkmcnt(0)" ::: "memory");          \
        __builtin_amdgcn_s_barrier();                                        \
        __builtin_amdgcn_sched_barrier(0);                                   \
        bc = bc + 1; if (bc >= 3) bc -= 3;                                   \
        ++t;                                                                 \
    }

    // ---- prologue ----
    ISSUEA(pA, 0);
    __builtin_amdgcn_sched_barrier(0);
    STAGEB(0, 0);
    __builtin_amdgcn_sched_barrier(0);
    WRITEA(0, pA);                           // implicit wait A(0); B(0) in flight
    ISSUEA(pA, 1);
    __builtin_amdgcn_sched_barrier(0);
    STAGEB(1, 1);
    __builtin_amdgcn_sched_barrier(0);
    asm volatile("s_waitcnt vmcnt(8) lgkmcnt(0)" ::: "memory");  // B(0) landed
    __builtin_amdgcn_s_barrier();
    __builtin_amdgcn_sched_barrier(0);

    // ---- main loop: steps 0..13 (prefetch up to step 15) ----
    int t = 0, bc = 0;
    for (int it = 0; it < 7; ++it){
        STEP(pA, nA);
        STEP(nA, pA);
    }
    // ---- tail: t==14, bc==2, pA holds A(15) ----
    COMPUTE(0, 2);                           // step 14: lA[0], lB[14%3=2]
    __builtin_amdgcn_sched_barrier(0);
    WRITEA(1, pA);                           // A(15)
    asm volatile("s_waitcnt vmcnt(0) lgkmcnt(0)" ::: "memory");
    __builtin_amdgcn_s_barrier();
    __builtin_amdgcn_sched_barrier(0);
    COMPUTE(1, 0);                           // step 15: lA[1], lB[15%3=0]

    // ---- epilogue: store raw partial (pre-bias, pre-LN) as bf16 ----
    __bf16* dst = H1p + (size_t)kBlk * 16384 * 256;
#pragma unroll
    for (int m = 0; m < 4; ++m)
#pragma unroll
        for (int r = 0; r < 4; ++r){
            size_t row = (size_t)(mBase + wm*64 + m*16 + lg*4 + r);
#pragma unroll
            for (int n = 0; n < 4; ++n){
                int col = wn*64 + n*16 + l15;
                dst[row*256 + col] = (__bf16)acc[m][n][r];
            }
        }
#undef ISSUEA
#undef STAGEB
#undef WRITEA
#undef COMPUTE
#undef STEP
}

// ---------- K1b: H1 = gelu(LN(partA + partB + b1)); writes in place over partB ----------
// 8 waves/block, one wave per row (256 cols = 64 lanes x 4). 1:1 element map -> no race.
__global__ __launch_bounds__(512) void ln_gelu_k(
    const __bf16* __restrict__ pA_, __bf16* __restrict__ pB_,
    const float* __restrict__ b1, const float* __restrict__ g1,
    const float* __restrict__ be1)
{
    const int row  = blockIdx.x * 8 + (threadIdx.x >> 6);
    const int lane = threadIdx.x & 63;
    const int c0   = lane * 4;

    bf16x4 a = *(const bf16x4*)&pA_[(size_t)row*256 + c0];
    bf16x4 b = *(const bf16x4*)&pB_[(size_t)row*256 + c0];
    float x[4];
    float s = 0.f, q = 0.f;
#pragma unroll
    for (int e = 0; e < 4; ++e){
        x[e] = (float)a[e] + (float)b[e] + b1[c0 + e];
        s += x[e]; q += x[e]*x[e];
    }
#pragma unroll
    for (int off = 1; off <= 32; off <<= 1){
        s += __shfl_xor(s, off, 64);
        q += __shfl_xor(q, off, 64);
    }
    float mu  = s * (1.f/256.f);
    float var = q * (1.f/256.f) - mu*mu;
    float rs  = rsqrtf(var + 1e-5f);
    bf16x4 o;
#pragma unroll
    for (int e = 0; e < 4; ++e)
        o[e] = (__bf16)gelu_exact((x[e] - mu) * rs * g1[c0 + e] + be1[c0 + e]);
    *(bf16x4*)&pB_[(size_t)row*256 + c0] = o;
}

// ---------- K2: fused tail ----------
__global__ __launch_bounds__(512) void tail_fused(
    const __bf16* __restrict__ H1, const __bf16* __restrict__ W2T,
    const float* __restrict__ b2, const float* __restrict__ g2,
    const float* __restrict__ be2, const float* __restrict__ W3,
    const float* __restrict__ b3, const int* __restrict__ labels,
    const float* __restrict__ temperature, float* __restrict__ ADJ)
{
    __shared__ union { __bf16 lH[64*256]; float h2[64*128]; } u;
    __shared__ __bf16 lW[128*256];
    __shared__ float  redS[64][4];
    __shared__ float  redQ[64][4];
    __shared__ float  lw3[256];

    const int tid  = threadIdx.x;
    const int wid  = tid >> 6;
    const int lane = tid & 63;
    const int l15  = lane & 15;
    const int lg   = lane >> 4;
    const int wm   = wid >> 2, wn = wid & 3;
    const int mBase = blockIdx.x * 64;

    {
        int r0 = tid >> 5;
        int c8 = (tid & 31) * 8;
        int swz = c8 ^ ((r0 & 7) << 3);
#pragma unroll
        for (int i = 0; i < 4; ++i){
            int row = r0 + i*16;
            bf16x8 v = *(const bf16x8*)&H1[(size_t)(mBase+row)*256 + c8];
            *(bf16x8*)&u.lH[row*256 + swz] = v;
        }
#pragma unroll
        for (int i = 0; i < 8; ++i){
            int row = r0 + i*16;
            bf16x8 v = *(const bf16x8*)&W2T[(size_t)row*256 + c8];
            *(bf16x8*)&lW[row*256 + swz] = v;
        }
        if (tid < 256) lw3[tid] = W3[tid];
    }
    __syncthreads();

    f32x4 acc[2][2] = {};
#pragma unroll
    for (int kk = 0; kk < 8; ++kk){
        const int kcol = kk*32 + lg*8;
        bf16x8 av[2], bv[2];
#pragma unroll
        for (int m = 0; m < 2; ++m){
            int row = wm*32 + m*16 + l15;
            av[m] = *(const bf16x8*)&u.lH[row*256 + (kcol ^ ((row&7)<<3))];
        }
#pragma unroll
        for (int n = 0; n < 2; ++n){
            int row = wn*32 + n*16 + l15;
            bv[n] = *(const bf16x8*)&lW[row*256 + (kcol ^ ((row&7)<<3))];
        }
#pragma unroll
        for (int m = 0; m < 2; ++m)
#pragma unroll
            for (int n = 0; n < 2; ++n)
                acc[m][n] = MFMA16(av[m], bv[n], acc[m][n]);
    }

    float b2_[2], g2_[2], be_[2];
#pragma unroll
    for (int n = 0; n < 2; ++n){
        int col = wn*32 + n*16 + l15;
        b2_[n] = b2[col]; g2_[n] = g2[col]; be_[n] = be2[col];
    }
#pragma unroll
    for (int m = 0; m < 2; ++m)
#pragma unroll
        for (int n = 0; n < 2; ++n)
#pragma unroll
            for (int r = 0; r < 4; ++r)
                acc[m][n][r] += b2_[n];

#pragma unroll
    for (int m = 0; m < 2; ++m)
#pragma unroll
        for (int r = 0; r < 4; ++r){
            float s = 0.f, q = 0.f;
#pragma unroll
            for (int n = 0; n < 2; ++n){ float v = acc[m][n][r]; s += v; q += v*v; }
#pragma unroll
            for (int off = 1; off <= 8; off <<= 1){
                s += __shfl_xor(s, off, 64);
                q += __shfl_xor(q, off, 64);
            }
            int row = wm*32 + m*16 + lg*4 + r;
            if (l15 == 0){ redS[row][wn] = s; redQ[row][wn] = q; }
        }
    __syncthreads();

#pragma unroll
    for (int m = 0; m < 2; ++m)
#pragma unroll
        for (int r = 0; r < 4; ++r){
            int row = wm*32 + m*16 + lg*4 + r;
            float su = redS[row][0]+redS[row][1]+redS[row][2]+redS[row][3];
            float qu = redQ[row][0]+redQ[row][1]+redQ[row][2]+redQ[row][3];
            float mu  = su * (1.f/128.f);
            float var = qu * (1.f/128.f) - mu*mu;
            float rs  = rsqrtf(var + 1e-5f);
#pragma unroll
            for (int n = 0; n < 2; ++n){
                int col = wn*32 + n*16 + l15;
                float x = acc[m][n][r];
                float h = gelu_exact((x - mu)*rs*g2_[n] + be_[n]);
                u.h2[row*128 + (col ^ (row & 31))] = h;
            }
        }
    __syncthreads();

    if (tid < 64){
        const int row = tid;
        const int g = mBase + row;
        float a0 = b3[0], a1 = b3[1];
        for (int k = 0; k < 128; ++k){
            float v = u.h2[row*128 + (k ^ (row & 31))];
            a0 += v * lw3[2*k];
            a1 += v * lw3[2*k+1];
        }
        float t = fmaxf(temperature[0], 0.1f);
        float adj0 = tanhf(a0) * 0.1f;
        float adj1 = tanhf(a1) * 0.1f;
        bool crit = labels[g] > 0;
        float base0 = crit ? 0.25f : 0.75f;
        float base1 = crit ? 0.75f : 0.25f;
        float L0 = (base0 + adj0) / t, L1 = (base1 + adj1) / t;
        float mm = fmaxf(L0, L1);
        float e0 = expf(L0 - mm), e1 = expf(L1 - mm);
        float inv = 1.f / (e0 + e1);
        ADJ[(size_t)g*2    ] = e0 * inv;
        ADJ[(size_t)g*2 + 1] = e1 * inv;
    }
}

// ---------- K3: EMA as 128-tap truncated convolution ----------
__global__ void ema_kernel(const float* __restrict__ ADJ, float* __restrict__ out)
{
    __shared__ float wtab[128];
    __shared__ float abuf[384*2];
    const int b     = blockIdx.x >> 2;
    const int chunk = blockIdx.x & 3;
    const int c0    = chunk * 256;
    const int tid   = threadIdx.x;
    if (tid < 128) wtab[tid] = powf(0.9f, (float)tid);
    for (int idx = tid; idx < 768; idx += 256){
        int tt = c0 - 128 + (idx >> 1);
        int cc = idx & 1;
        abuf[idx] = (tt >= 0) ? ADJ[((size_t)b*1024 + tt)*2 + cc] : 0.f;
    }
    __syncthreads();
#pragma unroll
    for (int i = 0; i < 2; ++i){
        int item = tid + i*256;
        int tl = item >> 1, cc = item & 1;
        int t = c0 + tl;
        int kmax = min(t, 127);
        float sum = 0.f;
        for (int k = 0; k <= kmax; ++k){
            float coef = (t - k == 0) ? wtab[k] : 0.1f * wtab[k];
            sum += coef * abuf[(tl - k + 128)*2 + cc];
        }
        out[((size_t)b*1024 + t)*2 + cc] = sum;
    }
}

extern "C" void kernel_launch(void* const* d_in, const int* in_sizes, int n_in,
                              void* d_out, int out_size, void* d_ws, size_t ws_size,
                              hipStream_t stream)
{
    const int*   labels = (const int*)  d_in[0];
    const float* X      = (const float*)d_in[1];
    const float* W1     = (const float*)d_in[2];
    const float* b1     = (const float*)d_in[3];
    const float* g1     = (const float*)d_in[4];
    const float* be1    = (const float*)d_in[5];
    const float* W2     = (const float*)d_in[6];
    const float* b2     = (const float*)d_in[7];
    const float* g2     = (const float*)d_in[8];
    const float* be2    = (const float*)d_in[9];
    const float* W3     = (const float*)d_in[10];
    const float* b3     = (const float*)d_in[11];
    const float* temp   = (const float*)d_in[12];
    float* out = (float*)d_out;

    char* ws = (char*)d_ws;
    __bf16* W1T  = (__bf16*)(ws);                  // 256 x 2048 bf16   (1 MiB)
    __bf16* W2T  = (__bf16*)(ws + 1048576);        // 128 x 256  bf16   (64 KiB)
    __bf16* H1pA = (__bf16*)(ws + 1114112);        // partial k0, 8 MiB
    __bf16* H1pB = (__bf16*)(ws + 9502720);        // partial k1 -> H1 in place, 8 MiB
    float*  ADJ  = (float*)(ws + 17891328);        // 16384 x 2 f32     (128 KiB)

    transp_bf16<<<256, 256, 0, stream>>>(W1, W1T, 2048, 256);
    transp_bf16<<<32,  256, 0, stream>>>(W2, W2T, 256, 128);
    gemm1_pre<<<256, 512, 0, stream>>>(X, W1T, H1pA);          // kBlk=1 lands at H1pB
    ln_gelu_k<<<2048, 512, 0, stream>>>(H1pA, H1pB, b1, g1, be1);
    tail_fused<<<256, 512, 0, stream>>>(H1pB, W2T, b2, g2, be2, W3, b3, labels, temp, ADJ);
    ema_kernel<<<64, 256, 0, stream>>>(ADJ, out);
}